// Round 5
// baseline (116.914 us; speedup 1.0000x reference)
//
#include <hip/hip_runtime.h>
#include <hip/hip_bf16.h>
#include <math.h>

#define TT 512
#define CC 1024
#define NH 16
#define NKV 8
#define HD 64
static constexpr float EPS_ = 1e-6f;

typedef short bf16x8 __attribute__((ext_vector_type(8)));
typedef float f32x4 __attribute__((ext_vector_type(4)));

__device__ __forceinline__ ushort f2bf(float f) {
  union { __hip_bfloat16 h; ushort u; } cv;
  cv.h = __float2bfloat16(f);
  return cv.u;
}

// ---------------------------------------------------------------------------
// prep: x -> bf16 (same layout); Wq/Wk/Wv/Wo -> transposed bf16 Wt[n][k]
// ---------------------------------------------------------------------------
__global__ __launch_bounds__(256) void prep_kernel(
    const float* __restrict__ x,
    const float* __restrict__ Wq, const float* __restrict__ Wk,
    const float* __restrict__ Wv, const float* __restrict__ Wo,
    ushort* __restrict__ xb, ushort* __restrict__ Wtq, ushort* __restrict__ Wtk,
    ushort* __restrict__ Wtv, ushort* __restrict__ Wto)
{
  int b = blockIdx.x;
  if (b < 256) {
    int base = b * 2048 + threadIdx.x * 8;
    float4 f0 = *reinterpret_cast<const float4*>(&x[base]);
    float4 f1 = *reinterpret_cast<const float4*>(&x[base + 4]);
    union { ushort u[8]; uint4 v; } pk;
    pk.u[0] = f2bf(f0.x); pk.u[1] = f2bf(f0.y); pk.u[2] = f2bf(f0.z); pk.u[3] = f2bf(f0.w);
    pk.u[4] = f2bf(f1.x); pk.u[5] = f2bf(f1.y); pk.u[6] = f2bf(f1.z); pk.u[7] = f2bf(f1.w);
    *reinterpret_cast<uint4*>(&xb[base]) = pk.v;
    return;
  }
  b -= 256;
  const float* W; ushort* Wt; int ldW, tr, tc;
  if (b < 256)      { W = Wq; Wt = Wtq; ldW = 1024; tr = b >> 4;       tc = b & 15; }
  else if (b < 384) { int q = b - 256; W = Wk; Wt = Wtk; ldW = 512; tr = q >> 3; tc = q & 7; }
  else if (b < 512) { int q = b - 384; W = Wv; Wt = Wtv; ldW = 512; tr = q >> 3; tc = q & 7; }
  else              { int q = b - 512; W = Wo; Wt = Wto; ldW = 1024; tr = q >> 4; tc = q & 15; }
  const int k0 = tr * 64, n0 = tc * 64;
  __shared__ float ft[64][65];
  const int t = threadIdx.x;
#pragma unroll
  for (int it = 0; it < 4; ++it) {
    int q = t + it * 256;
    int r = q >> 4, c4 = q & 15;
    float4 f = *reinterpret_cast<const float4*>(&W[(k0 + r) * ldW + n0 + c4 * 4]);
    ft[r][c4 * 4 + 0] = f.x; ft[r][c4 * 4 + 1] = f.y;
    ft[r][c4 * 4 + 2] = f.z; ft[r][c4 * 4 + 3] = f.w;
  }
  __syncthreads();
#pragma unroll
  for (int it = 0; it < 2; ++it) {
    int q = t + it * 256;
    int n = q >> 3, kc = q & 7;
    union { ushort u[8]; uint4 v; } pk;
#pragma unroll
    for (int j = 0; j < 8; ++j) pk.u[j] = f2bf(ft[kc * 8 + j][n]);
    *reinterpret_cast<uint4*>(&Wt[(n0 + n) * 1024 + k0 + kc * 8]) = pk.v;
  }
}

// ---------------------------------------------------------------------------
// bf16 MFMA GEMM: C[64x64 tile] = A[M][1024] @ Bt[N][1024]^T, fp32 out.
// ---------------------------------------------------------------------------
__device__ __forceinline__ void mfma_gemm64(
    const ushort* __restrict__ A, const ushort* __restrict__ Bt,
    float* __restrict__ C, int ldC, int row0, int col0)
{
  __shared__ ushort At[64][72];
  __shared__ ushort Bs[64][72];
  const int tid = threadIdx.x;
  const int lane = tid & 63, w = tid >> 6;
  const int m0 = (w & 1) * 32, n0 = (w >> 1) * 32;
  const int lr = lane & 15, lk = (lane >> 4) * 8;
  f32x4 acc[2][2] = {};
  const int sr = tid >> 2;
  const int sc = (tid & 3) * 16;
  const ushort* Ap = &A[(row0 + sr) * 1024 + sc];
  const ushort* Bp = &Bt[(col0 + sr) * 1024 + sc];

  for (int k0 = 0; k0 < 1024; k0 += 64) {
    __syncthreads();
    uint4 a0 = *reinterpret_cast<const uint4*>(Ap + k0);
    uint4 a1 = *reinterpret_cast<const uint4*>(Ap + k0 + 8);
    uint4 b0 = *reinterpret_cast<const uint4*>(Bp + k0);
    uint4 b1 = *reinterpret_cast<const uint4*>(Bp + k0 + 8);
    *reinterpret_cast<uint4*>(&At[sr][sc]) = a0;
    *reinterpret_cast<uint4*>(&At[sr][sc + 8]) = a1;
    *reinterpret_cast<uint4*>(&Bs[sr][sc]) = b0;
    *reinterpret_cast<uint4*>(&Bs[sr][sc + 8]) = b1;
    __syncthreads();
#pragma unroll
    for (int kk = 0; kk < 2; ++kk) {
      bf16x8 af[2], bg[2];
      af[0] = *reinterpret_cast<const bf16x8*>(&At[m0 + lr][kk * 32 + lk]);
      af[1] = *reinterpret_cast<const bf16x8*>(&At[m0 + 16 + lr][kk * 32 + lk]);
      bg[0] = *reinterpret_cast<const bf16x8*>(&Bs[n0 + lr][kk * 32 + lk]);
      bg[1] = *reinterpret_cast<const bf16x8*>(&Bs[n0 + 16 + lr][kk * 32 + lk]);
#pragma unroll
      for (int mi = 0; mi < 2; ++mi)
#pragma unroll
        for (int ni = 0; ni < 2; ++ni)
          acc[mi][ni] = __builtin_amdgcn_mfma_f32_16x16x32_bf16(af[mi], bg[ni], acc[mi][ni], 0, 0, 0);
    }
  }
  const int crow = (lane >> 4) * 4, ccol = lane & 15;
#pragma unroll
  for (int mi = 0; mi < 2; ++mi)
#pragma unroll
    for (int ni = 0; ni < 2; ++ni) {
      int rb = row0 + m0 + mi * 16 + crow;
      int cc = col0 + n0 + ni * 16 + ccol;
#pragma unroll
      for (int r = 0; r < 4; ++r)
        C[(rb + r) * ldC + cc] = acc[mi][ni][r];
    }
}

__global__ __launch_bounds__(256) void qkv_mfma_kernel(
    const ushort* __restrict__ xb,
    const ushort* __restrict__ Wtq, const ushort* __restrict__ Wtk, const ushort* __restrict__ Wtv,
    float* __restrict__ qb, float* __restrict__ kb, float* __restrict__ vb)
{
  int bx = blockIdx.x, by = blockIdx.y;
  if (bx < 16)      mfma_gemm64(xb, Wtq, qb, 1024, by * 64, bx * 64);
  else if (bx < 24) mfma_gemm64(xb, Wtk, kb, 512, by * 64, (bx - 16) * 64);
  else              mfma_gemm64(xb, Wtv, vb, 512, by * 64, (bx - 24) * 64);
}

__global__ __launch_bounds__(256) void out_mfma_kernel(
    const ushort* __restrict__ yb, const ushort* __restrict__ Wto, float* __restrict__ out)
{
  mfma_gemm64(yb, Wto, out, 1024, blockIdx.y * 64, blockIdx.x * 64);
}

// ---------------------------------------------------------------------------
// RoPE + RMS-norm, in place (fp32).
// ---------------------------------------------------------------------------
__global__ __launch_bounds__(256) void rope_rms_kernel(
    float* __restrict__ qb, float* __restrict__ kb,
    const float* __restrict__ cosb, const float* __restrict__ sinb)
{
  int rid = blockIdx.x * 4 + (threadIdx.x >> 6);
  int lane = threadIdx.x & 63;
  float* p; int t;
  if (rid < TT * NH) { t = rid >> 4; p = qb + t * 1024 + (rid & 15) * 64; }
  else { int r2 = rid - TT * NH; t = r2 >> 3; p = kb + t * 512 + (r2 & 7) * 64; }

  float v = p[lane];
  float part = __shfl_xor(v, 32);
  int f = lane & 31;
  float c = cosb[t * 32 + f], s = sinb[t * 32 + f];
  float o = (lane < 32) ? (v * c - part * s) : (part * s + v * c);
  float ss = o * o;
#pragma unroll
  for (int off = 32; off; off >>= 1) ss += __shfl_xor(ss, off);
  float r = rsqrtf(ss * (1.0f / 64.0f) + EPS_);
  p[lane] = o * r;
}

// ---------------------------------------------------------------------------
// Tropical causal attention, v4: split-K partials.
// Deferred softmax (scores bounded since q,k RMS-normed -> exp safe, sums
// associative). Block = (head h, 16-row q-chunk c, 128-wide j-group jg).
// Active iff jg <= c/8. Each block: <=2 j-tiles of 64; 4 waves x 4 q-rows.
// Partials: pacc[slot][16][64] (fp32) + plsum[slot][16]; combined later.
// Slot packing: slot = h*80 + cum(c) + jg, cum(c) = c + 4A(A-1) + B*A,
// A=c/8, B=c%8  (sum over c'<c of (c'/8+1)).
// No spills by construction: kreg[64]+vreg[64]+acc ~ 160 VGPR, bounds(256,2).
// ---------------------------------------------------------------------------
__global__ __launch_bounds__(256, 2) void attn_part_kernel(
    const float* __restrict__ qb, const float* __restrict__ kb,
    const float* __restrict__ vb, float* __restrict__ pacc,
    float* __restrict__ plsum)
{
  __shared__ float kS[64][76];
  __shared__ float vS[64][76];
  __shared__ __align__(16) float qS[16][64];
  __shared__ __align__(16) float pS[4][4][64];

  const int tid = threadIdx.x;
  const int w = tid >> 6, lane = tid & 63;
  const int bx = blockIdx.x;
  const int h = bx & 15, c = (bx >> 4) & 31, jg = bx >> 9;
  const int A = c >> 3;
  if (jg > A) return;
  const int g = h >> 1;
  const int i0 = c * 16;
  const int cum = c + 4 * A * (A - 1) + (c & 7) * A;
  const int slot = h * 80 + cum + jg;

  // stage q (16 rows x 64)
  {
    int r = tid >> 4, c4 = tid & 15;
    *reinterpret_cast<float4*>(&qS[r][c4 * 4]) =
        *reinterpret_cast<const float4*>(&qb[(i0 + r) * 1024 + h * 64 + c4 * 4]);
  }

  float acc[4] = {0.f, 0.f, 0.f, 0.f};
  float ls[4]  = {0.f, 0.f, 0.f, 0.f};

  const int jt_beg = jg * 2;
  const int jt_end = min(jg * 2 + 2, (i0 >> 6) + 1);

  for (int jt = jt_beg; jt < jt_end; ++jt) {
    const int j0 = jt * 64;
    __syncthreads();                       // LDS reusable (also orders q-stage)
#pragma unroll
    for (int it = 0; it < 4; ++it) {
      int s = tid + it * 256;
      int r = s >> 4, c4 = s & 15;
      *reinterpret_cast<float4*>(&kS[r][c4 * 4]) =
          *reinterpret_cast<const float4*>(&kb[(j0 + r) * 512 + g * 64 + c4 * 4]);
      *reinterpret_cast<float4*>(&vS[r][c4 * 4]) =
          *reinterpret_cast<const float4*>(&vb[(j0 + r) * 512 + g * 64 + c4 * 4]);
    }
    __syncthreads();

    // K row (j = j0+lane) into registers
    float kreg[64];
#pragma unroll
    for (int d4 = 0; d4 < 16; ++d4)
      *reinterpret_cast<float4*>(&kreg[d4 * 4]) =
          *reinterpret_cast<const float4*>(&kS[lane][d4 * 4]);
    // V column (d = lane) into registers
    float vreg[64];
#pragma unroll
    for (int j = 0; j < 64; ++j) vreg[j] = vS[j][lane];

    // scores + exp + per-row partial sum
#pragma unroll
    for (int q = 0; q < 4; ++q) {
      const int i = i0 + 4 * w + q;
      const float4* q4 = reinterpret_cast<const float4*>(qS[4 * w + q]);
      float s0 = -INFINITY, s1 = -INFINITY;
#pragma unroll
      for (int d4 = 0; d4 < 16; ++d4) {
        float4 qv = q4[d4];
        s0 = fmaxf(fmaxf(s0, qv.x + kreg[d4 * 4 + 0]), qv.y + kreg[d4 * 4 + 1]);
        s1 = fmaxf(fmaxf(s1, qv.z + kreg[d4 * 4 + 2]), qv.w + kreg[d4 * 4 + 3]);
      }
      float s = fmaxf(s0, s1);
      if (j0 + lane > i) s = -INFINITY;
      float pp = __expf(s);                // bounded: q,k RMS-normed
      float l = pp;
#pragma unroll
      for (int off = 32; off; off >>= 1) l += __shfl_xor(l, off);
      ls[q] += l;
      pS[w][q][lane] = pp;
    }

    // PV: register-resident V column, broadcast P reads (same-wave RAW)
#pragma unroll
    for (int q = 0; q < 4; ++q) {
      const float4* p4 = reinterpret_cast<const float4*>(pS[w][q]);
      float a = acc[q];
#pragma unroll
      for (int j4 = 0; j4 < 16; ++j4) {
        float4 pv = p4[j4];
        a = fmaf(pv.x, vreg[j4 * 4 + 0], a);
        a = fmaf(pv.y, vreg[j4 * 4 + 1], a);
        a = fmaf(pv.z, vreg[j4 * 4 + 2], a);
        a = fmaf(pv.w, vreg[j4 * 4 + 3], a);
      }
      acc[q] = a;
    }
  }

  // store partials
#pragma unroll
  for (int q = 0; q < 4; ++q) {
    int r = 4 * w + q;
    pacc[slot * 1024 + r * 64 + lane] = acc[q];
    if (lane == 0) plsum[slot * 16 + r] = ls[q];
  }
}

// ---------------------------------------------------------------------------
// Combine split-K partials: y = (sum acc)/(sum l), write bf16.
// Block per (h, c): 512 blocks.
// ---------------------------------------------------------------------------
__global__ __launch_bounds__(256) void attn_combine_kernel(
    const float* __restrict__ pacc, const float* __restrict__ plsum,
    ushort* __restrict__ yb)
{
  const int bx = blockIdx.x;
  const int h = bx & 15, c = bx >> 4;
  const int A = c >> 3;
  const int njg = A + 1;
  const int cum = c + 4 * A * (A - 1) + (c & 7) * A;
  const int sb = h * 80 + cum;
  const int tid = threadIdx.x;
  const int w = tid >> 6, lane = tid & 63;

#pragma unroll
  for (int q = 0; q < 4; ++q) {
    int r = 4 * w + q;
    float a = 0.f, l = 0.f;
    for (int jg = 0; jg < njg; ++jg) {
      a += pacc[(sb + jg) * 1024 + r * 64 + lane];
      l += plsum[(sb + jg) * 16 + r];
    }
    int i = c * 16 + r;
    yb[i * 1024 + h * 64 + lane] = f2bf(a / l);
  }
}

// ---------------------------------------------------------------------------
extern "C" void kernel_launch(void* const* d_in, const int* in_sizes, int n_in,
                              void* d_out, int out_size, void* d_ws, size_t ws_size,
                              hipStream_t stream) {
  const float* x    = (const float*)d_in[0];
  const float* cosb = (const float*)d_in[1];
  const float* sinb = (const float*)d_in[2];
  const float* Wq   = (const float*)d_in[3];
  const float* Wk   = (const float*)d_in[4];
  const float* Wv   = (const float*)d_in[5];
  const float* Wo   = (const float*)d_in[6];
  float* out = (float*)d_out;

  float* wsf = (float*)d_ws;
  float* qbuf = wsf;                      // 512x1024 f32
  float* kbuf = qbuf + TT * CC;           // 512x512  f32
  float* vbuf = kbuf + TT * 512;          // 512x512  f32
  float* pacc = vbuf + TT * 512;          // 1280 x 1024 f32 partial acc
  float* plsum = pacc + 1280 * 1024;      // 1280 x 16 f32 partial lsum
  ushort* wsu = (ushort*)(plsum + 1280 * 16);
  ushort* xb  = wsu;                      // 512x1024 bf16
  ushort* yb  = xb + TT * CC;             // 512x1024 bf16
  ushort* Wtq = yb + TT * CC;             // 1024x1024 bf16
  ushort* Wtk = Wtq + CC * CC;            // 512x1024 bf16
  ushort* Wtv = Wtk + 512 * CC;           // 512x1024 bf16
  ushort* Wto = Wtv + 512 * CC;           // 1024x1024 bf16

  prep_kernel<<<dim3(1024), 256, 0, stream>>>(x, Wq, Wk, Wv, Wo, xb, Wtq, Wtk, Wtv, Wto);
  qkv_mfma_kernel<<<dim3(32, 8), 256, 0, stream>>>(xb, Wtq, Wtk, Wtv, qbuf, kbuf, vbuf);
  rope_rms_kernel<<<dim3((TT * NH + TT * NKV) / 4), 256, 0, stream>>>(qbuf, kbuf, cosb, sinb);
  attn_part_kernel<<<dim3(2048), 256, 0, stream>>>(qbuf, kbuf, vbuf, pacc, plsum);
  attn_combine_kernel<<<dim3(512), 256, 0, stream>>>(pacc, plsum, yb);
  out_mfma_kernel<<<dim3(16, 8), 256, 0, stream>>>(yb, Wto, out);
}

// Round 6
// 76.152 us; speedup vs baseline: 1.5353x; 1.5353x over previous
//
#include <hip/hip_runtime.h>
#include <hip/hip_bf16.h>
#include <math.h>

#define TT 512
#define CC 1024
#define NH 16
#define NKV 8
#define HD 64
static constexpr float EPS_ = 1e-6f;

typedef short bf16x8 __attribute__((ext_vector_type(8)));
typedef float f32x4 __attribute__((ext_vector_type(4)));

__device__ __forceinline__ ushort f2bf(float f) {
  union { __hip_bfloat16 h; ushort u; } cv;
  cv.h = __float2bfloat16(f);
  return cv.u;
}

__device__ __forceinline__ void gload16(const ushort* g, ushort* l) {
  __builtin_amdgcn_global_load_lds(
      (const __attribute__((address_space(1))) unsigned int*)g,
      (__attribute__((address_space(3))) unsigned int*)l, 16, 0, 0);
}

// ---------------------------------------------------------------------------
// prep: x -> bf16 (same layout); Wq/Wk/Wv/Wo -> transposed bf16 Wt[n][k]
// ---------------------------------------------------------------------------
__global__ __launch_bounds__(256) void prep_kernel(
    const float* __restrict__ x,
    const float* __restrict__ Wq, const float* __restrict__ Wk,
    const float* __restrict__ Wv, const float* __restrict__ Wo,
    ushort* __restrict__ xb, ushort* __restrict__ Wtq, ushort* __restrict__ Wtk,
    ushort* __restrict__ Wtv, ushort* __restrict__ Wto)
{
  int b = blockIdx.x;
  if (b < 256) {
    int base = b * 2048 + threadIdx.x * 8;
    float4 f0 = *reinterpret_cast<const float4*>(&x[base]);
    float4 f1 = *reinterpret_cast<const float4*>(&x[base + 4]);
    union { ushort u[8]; uint4 v; } pk;
    pk.u[0] = f2bf(f0.x); pk.u[1] = f2bf(f0.y); pk.u[2] = f2bf(f0.z); pk.u[3] = f2bf(f0.w);
    pk.u[4] = f2bf(f1.x); pk.u[5] = f2bf(f1.y); pk.u[6] = f2bf(f1.z); pk.u[7] = f2bf(f1.w);
    *reinterpret_cast<uint4*>(&xb[base]) = pk.v;
    return;
  }
  b -= 256;
  const float* W; ushort* Wt; int ldW, tr, tc;
  if (b < 256)      { W = Wq; Wt = Wtq; ldW = 1024; tr = b >> 4;       tc = b & 15; }
  else if (b < 384) { int q = b - 256; W = Wk; Wt = Wtk; ldW = 512; tr = q >> 3; tc = q & 7; }
  else if (b < 512) { int q = b - 384; W = Wv; Wt = Wtv; ldW = 512; tr = q >> 3; tc = q & 7; }
  else              { int q = b - 512; W = Wo; Wt = Wto; ldW = 1024; tr = q >> 4; tc = q & 15; }
  const int k0 = tr * 64, n0 = tc * 64;
  __shared__ float ft[64][65];
  const int t = threadIdx.x;
#pragma unroll
  for (int it = 0; it < 4; ++it) {
    int q = t + it * 256;
    int r = q >> 4, c4 = q & 15;
    float4 f = *reinterpret_cast<const float4*>(&W[(k0 + r) * ldW + n0 + c4 * 4]);
    ft[r][c4 * 4 + 0] = f.x; ft[r][c4 * 4 + 1] = f.y;
    ft[r][c4 * 4 + 2] = f.z; ft[r][c4 * 4 + 3] = f.w;
  }
  __syncthreads();
#pragma unroll
  for (int it = 0; it < 2; ++it) {
    int q = t + it * 256;
    int n = q >> 3, kc = q & 7;
    union { ushort u[8]; uint4 v; } pk;
#pragma unroll
    for (int j = 0; j < 8; ++j) pk.u[j] = f2bf(ft[kc * 8 + j][n]);
    *reinterpret_cast<uint4*>(&Wt[(n0 + n) * 1024 + k0 + kc * 8]) = pk.v;
  }
}

// ---------------------------------------------------------------------------
// bf16 MFMA GEMM: C[64x64 tile] = A[M][1024] @ Bt[N][1024]^T, fp32 out.
// Linear LDS + global_load_lds width-16 staging (no VGPR round-trip).
// ---------------------------------------------------------------------------
__device__ __forceinline__ void mfma_gemm64(
    const ushort* __restrict__ A, const ushort* __restrict__ Bt,
    float* __restrict__ C, int ldC, int row0, int col0)
{
  __shared__ __align__(16) ushort At[64 * 64];
  __shared__ __align__(16) ushort Bs[64 * 64];
  const int tid = threadIdx.x;
  const int lane = tid & 63, w = tid >> 6;
  const int m0 = (w & 1) * 32, n0 = (w >> 1) * 32;
  const int lr = lane & 15, lk = (lane >> 4) * 8;
  f32x4 acc[2][2] = {};
  // staging: thread t -> linear 16B chunk t (row = t>>3, col8 = (t&7)*8)
  const int srow = tid >> 3, sc8 = (tid & 7) * 8;
  const ushort* Ap = &A[(row0 + srow) * 1024 + sc8];
  const ushort* Bp = &Bt[(col0 + srow) * 1024 + sc8];
  ushort* Al = &At[tid * 8];
  ushort* Bl = &Bs[tid * 8];

  for (int k0 = 0; k0 < 1024; k0 += 64) {
    __syncthreads();                       // prev compute done (drains counters)
    gload16(Ap + k0, Al);                  // rows 0..31
    gload16(Ap + 32 * 1024 + k0, Al + 2048);  // rows 32..63
    gload16(Bp + k0, Bl);
    gload16(Bp + 32 * 1024 + k0, Bl + 2048);
    __syncthreads();                       // vmcnt drained before barrier
#pragma unroll
    for (int kk = 0; kk < 2; ++kk) {
      bf16x8 af[2], bg[2];
      af[0] = *reinterpret_cast<const bf16x8*>(&At[(m0 + lr) * 64 + kk * 32 + lk]);
      af[1] = *reinterpret_cast<const bf16x8*>(&At[(m0 + 16 + lr) * 64 + kk * 32 + lk]);
      bg[0] = *reinterpret_cast<const bf16x8*>(&Bs[(n0 + lr) * 64 + kk * 32 + lk]);
      bg[1] = *reinterpret_cast<const bf16x8*>(&Bs[(n0 + 16 + lr) * 64 + kk * 32 + lk]);
#pragma unroll
      for (int mi = 0; mi < 2; ++mi)
#pragma unroll
        for (int ni = 0; ni < 2; ++ni)
          acc[mi][ni] = __builtin_amdgcn_mfma_f32_16x16x32_bf16(af[mi], bg[ni], acc[mi][ni], 0, 0, 0);
    }
  }
  const int crow = (lane >> 4) * 4, ccol = lane & 15;
#pragma unroll
  for (int mi = 0; mi < 2; ++mi)
#pragma unroll
    for (int ni = 0; ni < 2; ++ni) {
      int rb = row0 + m0 + mi * 16 + crow;
      int cc = col0 + n0 + ni * 16 + ccol;
#pragma unroll
      for (int r = 0; r < 4; ++r)
        C[(rb + r) * ldC + cc] = acc[mi][ni][r];
    }
}

__global__ __launch_bounds__(256) void qkv_mfma_kernel(
    const ushort* __restrict__ xb,
    const ushort* __restrict__ Wtq, const ushort* __restrict__ Wtk, const ushort* __restrict__ Wtv,
    float* __restrict__ qb, float* __restrict__ kb, float* __restrict__ vb)
{
  int bx = blockIdx.x, by = blockIdx.y;
  if (bx < 16)      mfma_gemm64(xb, Wtq, qb, 1024, by * 64, bx * 64);
  else if (bx < 24) mfma_gemm64(xb, Wtk, kb, 512, by * 64, (bx - 16) * 64);
  else              mfma_gemm64(xb, Wtv, vb, 512, by * 64, (bx - 24) * 64);
}

__global__ __launch_bounds__(256) void out_mfma_kernel(
    const ushort* __restrict__ yb, const ushort* __restrict__ Wto, float* __restrict__ out)
{
  mfma_gemm64(yb, Wto, out, 1024, blockIdx.y * 64, blockIdx.x * 64);
}

// ---------------------------------------------------------------------------
// RoPE + RMS-norm, in place (fp32).
// ---------------------------------------------------------------------------
__global__ __launch_bounds__(256) void rope_rms_kernel(
    float* __restrict__ qb, float* __restrict__ kb,
    const float* __restrict__ cosb, const float* __restrict__ sinb)
{
  int rid = blockIdx.x * 4 + (threadIdx.x >> 6);
  int lane = threadIdx.x & 63;
  float* p; int t;
  if (rid < TT * NH) { t = rid >> 4; p = qb + t * 1024 + (rid & 15) * 64; }
  else { int r2 = rid - TT * NH; t = r2 >> 3; p = kb + t * 512 + (r2 & 7) * 64; }

  float v = p[lane];
  float part = __shfl_xor(v, 32);
  int f = lane & 31;
  float c = cosb[t * 32 + f], s = sinb[t * 32 + f];
  float o = (lane < 32) ? (v * c - part * s) : (part * s + v * c);
  float ss = o * o;
#pragma unroll
  for (int off = 32; off; off >>= 1) ss += __shfl_xor(ss, off);
  float r = rsqrtf(ss * (1.0f / 64.0f) + EPS_);
  p[lane] = o * r;
}

// ---------------------------------------------------------------------------
// Tropical causal attention, v5.
// Block = (kv-head g, 8-row q-chunk), heavy-first. 4 waves: waves 0-1 ->
// head 2g, waves 2-3 -> head 2g+1; 4 q-rows per wave.
// Deferred softmax: scores bounded (q,k RMS-normed) -> p=exp(s) directly,
// per-lane lsum, ONE reduce at kernel end. No vreg (V read from LDS with
// conflict-free column b32, one read shared by 4 q-rows). Only kreg[64]
// register array -> no spills.
// ---------------------------------------------------------------------------
__global__ __launch_bounds__(256) void attn_kernel(
    const float* __restrict__ qb, const float* __restrict__ kb,
    const float* __restrict__ vb, ushort* __restrict__ yb)
{
  __shared__ float kS[64][76];
  __shared__ float vS[64][76];
  __shared__ __align__(16) float qS[16][64];
  __shared__ __align__(16) float pS[4][4][64];

  const int tid = threadIdx.x;
  const int w = tid >> 6, lane = tid & 63;
  const int bx = blockIdx.x;
  const int g = bx & 7;
  const int qc = 63 - (bx >> 3);        // heavy chunks first
  const int i0 = qc * 8;
  const int nt = (i0 >> 6) + 1;
  const int h = 2 * g + (w >> 1);
  const int rbase = 4 * (w & 1);        // row offset within this head's 8 rows
  const int qrow = (w >> 1) * 8 + rbase;

  // stage the 16 q rows (2 heads x 8 rows)
  {
    int r16 = tid >> 4, c4 = tid & 15;
    int hh = r16 >> 3, r = r16 & 7;
    *reinterpret_cast<float4*>(&qS[r16][c4 * 4]) =
        *reinterpret_cast<const float4*>(
            &qb[(i0 + r) * 1024 + (2 * g + hh) * 64 + c4 * 4]);
  }

  float acc[4] = {0.f, 0.f, 0.f, 0.f};
  float ls[4]  = {0.f, 0.f, 0.f, 0.f};

  for (int jt = 0; jt < nt; ++jt) {
    const int j0 = jt * 64;
    __syncthreads();                       // LDS reusable (also orders q-stage)
#pragma unroll
    for (int it = 0; it < 4; ++it) {
      int s = tid + it * 256;
      int r = s >> 4, c4 = s & 15;
      *reinterpret_cast<float4*>(&kS[r][c4 * 4]) =
          *reinterpret_cast<const float4*>(&kb[(j0 + r) * 512 + g * 64 + c4 * 4]);
      *reinterpret_cast<float4*>(&vS[r][c4 * 4]) =
          *reinterpret_cast<const float4*>(&vb[(j0 + r) * 512 + g * 64 + c4 * 4]);
    }
    __syncthreads();

    // K row (j = j0+lane) into registers
    float kreg[64];
#pragma unroll
    for (int d4 = 0; d4 < 16; ++d4)
      *reinterpret_cast<float4*>(&kreg[d4 * 4]) =
          *reinterpret_cast<const float4*>(&kS[lane][d4 * 4]);

    const bool lastT = (jt == nt - 1);

    // scores + exp (deferred softmax: no per-tile reduces)
#pragma unroll
    for (int q = 0; q < 4; ++q) {
      const int i = i0 + rbase + q;
      const float4* q4 = reinterpret_cast<const float4*>(qS[qrow + q]);
      float s0 = -INFINITY, s1 = -INFINITY;
#pragma unroll
      for (int d4 = 0; d4 < 16; ++d4) {
        float4 qv = q4[d4];
        s0 = fmaxf(fmaxf(s0, qv.x + kreg[d4 * 4 + 0]), qv.y + kreg[d4 * 4 + 1]);
        s1 = fmaxf(fmaxf(s1, qv.z + kreg[d4 * 4 + 2]), qv.w + kreg[d4 * 4 + 3]);
      }
      float s = fmaxf(s0, s1);
      if (lastT && (j0 + lane > i)) s = -INFINITY;
      float pp = __expf(s);                // bounded: q,k RMS-normed
      ls[q] += pp;                         // per-lane partial; reduce at end
      pS[w][q][lane] = pp;                 // same-wave RAW (in-order DS pipe)
    }

    // PV: outer j4; each V column element read once, shared by 4 q-rows
#pragma unroll
    for (int j4 = 0; j4 < 16; ++j4) {
      union { float4 v; float f[4]; } p0, p1, p2, p3;
      p0.v = *reinterpret_cast<const float4*>(&pS[w][0][j4 * 4]);
      p1.v = *reinterpret_cast<const float4*>(&pS[w][1][j4 * 4]);
      p2.v = *reinterpret_cast<const float4*>(&pS[w][2][j4 * 4]);
      p3.v = *reinterpret_cast<const float4*>(&pS[w][3][j4 * 4]);
#pragma unroll
      for (int u = 0; u < 4; ++u) {
        float vv = vS[j4 * 4 + u][lane];   // conflict-free: lanes consecutive
        acc[0] = fmaf(p0.f[u], vv, acc[0]);
        acc[1] = fmaf(p1.f[u], vv, acc[1]);
        acc[2] = fmaf(p2.f[u], vv, acc[2]);
        acc[3] = fmaf(p3.f[u], vv, acc[3]);
      }
    }
  }

  // epilogue: one lsum reduce per q-row, write y as bf16
#pragma unroll
  for (int q = 0; q < 4; ++q) {
    float l = ls[q];
#pragma unroll
    for (int off = 32; off; off >>= 1) l += __shfl_xor(l, off);
    int i = i0 + rbase + q;
    yb[i * 1024 + h * 64 + lane] = f2bf(acc[q] / l);
  }
}

// ---------------------------------------------------------------------------
extern "C" void kernel_launch(void* const* d_in, const int* in_sizes, int n_in,
                              void* d_out, int out_size, void* d_ws, size_t ws_size,
                              hipStream_t stream) {
  const float* x    = (const float*)d_in[0];
  const float* cosb = (const float*)d_in[1];
  const float* sinb = (const float*)d_in[2];
  const float* Wq   = (const float*)d_in[3];
  const float* Wk   = (const float*)d_in[4];
  const float* Wv   = (const float*)d_in[5];
  const float* Wo   = (const float*)d_in[6];
  float* out = (float*)d_out;

  float* wsf = (float*)d_ws;
  float* qbuf = wsf;                      // 512x1024 f32
  float* kbuf = qbuf + TT * CC;           // 512x512  f32
  float* vbuf = kbuf + TT * 512;          // 512x512  f32
  ushort* wsu = (ushort*)(vbuf + TT * 512);
  ushort* xb  = wsu;                      // 512x1024 bf16
  ushort* yb  = xb + TT * CC;             // 512x1024 bf16
  ushort* Wtq = yb + TT * CC;             // 1024x1024 bf16
  ushort* Wtk = Wtq + CC * CC;            // 512x1024 bf16
  ushort* Wtv = Wtk + 512 * CC;           // 512x1024 bf16
  ushort* Wto = Wtv + 512 * CC;           // 1024x1024 bf16

  prep_kernel<<<dim3(1024), 256, 0, stream>>>(x, Wq, Wk, Wv, Wo, xb, Wtq, Wtk, Wtv, Wto);
  qkv_mfma_kernel<<<dim3(32, 8), 256, 0, stream>>>(xb, Wtq, Wtk, Wtv, qbuf, kbuf, vbuf);
  rope_rms_kernel<<<dim3((TT * NH + TT * NKV) / 4), 256, 0, stream>>>(qbuf, kbuf, cosb, sinb);
  attn_kernel<<<dim3(512), 256, 0, stream>>>(qbuf, kbuf, vbuf, yb);
  out_mfma_kernel<<<dim3(16, 8), 256, 0, stream>>>(yb, Wto, out);
}